// Round 1
// baseline (940.561 us; speedup 1.0000x reference)
//
#include <hip/hip_runtime.h>
#include <math.h>

#define T_TOK 8192
#define DDIM  1024
#define FDIM  4096
#define NEXP  8

typedef __attribute__((ext_vector_type(8))) short short8;
typedef __attribute__((ext_vector_type(4))) float f32x4;
typedef unsigned short u16;
typedef unsigned int   u32;

typedef const __attribute__((address_space(1))) u32* gp_t;
typedef       __attribute__((address_space(3))) u32* lp_t;

__device__ __forceinline__ void gload16(const void* g, void* l) {
  __builtin_amdgcn_global_load_lds((gp_t)g, (lp_t)l, 16, 0, 0);
}

__device__ __forceinline__ u16 f2bf(float f) {
  u32 u = __float_as_uint(f);
  u = u + 0x7FFFu + ((u >> 16) & 1u);
  return (u16)(u >> 16);
}

__device__ __forceinline__ float gelu_exact(float v) {
  return 0.5f * v * (1.0f + erff(v * 0.70710678118654752440f));
}

// ---------------- router: one wave per token ----------------
__global__ __launch_bounds__(256) void router_kernel(
    const float* __restrict__ x, const float* __restrict__ gw,
    const float* __restrict__ gb, int* __restrict__ counts,
    int* __restrict__ sel, float* __restrict__ wts)
{
  const int t    = blockIdx.x * 4 + (threadIdx.x >> 6);
  const int lane = threadIdx.x & 63;
  const float* xr = x + (size_t)t * DDIM;
  float lg[NEXP];
  #pragma unroll
  for (int e = 0; e < NEXP; e++) lg[e] = 0.f;
  for (int i = 0; i < DDIM / 64; i++) {
    float xv = xr[lane + i * 64];
    const float* g = gw + (size_t)(lane + i * 64) * NEXP;
    #pragma unroll
    for (int e = 0; e < NEXP; e++) lg[e] += xv * g[e];
  }
  #pragma unroll
  for (int off = 32; off > 0; off >>= 1) {
    #pragma unroll
    for (int e = 0; e < NEXP; e++) lg[e] += __shfl_down(lg[e], off);
  }
  if (lane == 0) {
    float v0 = -1e30f, v1 = -1e30f; int s0 = 0, s1 = 0;
    #pragma unroll
    for (int e = 0; e < NEXP; e++) {
      float v = lg[e] + gb[e];
      if (v > v0) { v1 = v0; s1 = s0; v0 = v; s0 = e; }
      else if (v > v1) { v1 = v; s1 = e; }
    }
    float a  = expf(v1 - v0);
    float w0 = 1.f / (1.f + a);
    sel[t * 2] = s0; sel[t * 2 + 1] = s1;
    wts[t * 2] = w0; wts[t * 2 + 1] = 1.f - w0;
    atomicAdd(&counts[s0], 1); atomicAdd(&counts[s1], 1);
  }
}

__global__ void scan_kernel(const int* __restrict__ counts,
                            int* __restrict__ offsets, int* __restrict__ pos)
{
  if (threadIdx.x == 0) {
    int run = 0;
    for (int e = 0; e < NEXP; e++) { offsets[e] = run; pos[e] = run; run += counts[e]; }
  }
}

__global__ __launch_bounds__(256) void slot_assign_kernel(
    const int* __restrict__ sel, const float* __restrict__ wts,
    int* __restrict__ pos, int* __restrict__ slot_token,
    float* __restrict__ slot_weight, int* __restrict__ token_slot)
{
  const int t = blockIdx.x * 256 + threadIdx.x;
  #pragma unroll
  for (int k = 0; k < 2; k++) {
    int e = sel[t * 2 + k];
    int p = atomicAdd(&pos[e], 1);
    slot_token[p] = t; slot_weight[p] = wts[t * 2 + k];
    token_slot[t * 2 + k] = p;
  }
}

// ---------------- x -> bf16 ----------------
__global__ __launch_bounds__(256) void xconv_kernel(
    const float* __restrict__ x, u16* __restrict__ xb)
{
  size_t i = ((size_t)blockIdx.x * 256 + threadIdx.x) * 8;
  float4 a = *(const float4*)&x[i];
  float4 b = *(const float4*)&x[i + 4];
  uint4 o;
  o.x = (u32)f2bf(a.x) | ((u32)f2bf(a.y) << 16);
  o.y = (u32)f2bf(a.z) | ((u32)f2bf(a.w) << 16);
  o.z = (u32)f2bf(b.x) | ((u32)f2bf(b.y) << 16);
  o.w = (u32)f2bf(b.z) | ((u32)f2bf(b.w) << 16);
  *(uint4*)&xb[i] = o;
}

// ---------------- weight transpose + bf16: in [M][N] f32 -> out [N][M] bf16 ----
__global__ __launch_bounds__(256) void wtrans_kernel(
    const float* __restrict__ in, u16* __restrict__ out, int M, int N)
{
  const int e = blockIdx.z;
  in  += (size_t)e * M * N;
  out += (size_t)e * M * N;
  const int c0 = blockIdx.x * 64;
  const int r0 = blockIdx.y * 64;
  __shared__ float tile[64][65];
  const int tid = threadIdx.x;
  const int tr = tid >> 4;
  const int tc = (tid & 15) * 4;
  #pragma unroll
  for (int p = 0; p < 4; p++) {
    int r = p * 16 + tr;
    float4 v = *(const float4*)(in + (size_t)(r0 + r) * N + (c0 + tc));
    tile[r][tc] = v.x; tile[r][tc + 1] = v.y; tile[r][tc + 2] = v.z; tile[r][tc + 3] = v.w;
  }
  __syncthreads();
  #pragma unroll
  for (int p = 0; p < 4; p++) {
    int oc = p * 16 + tr;
    ushort4 o;
    o.x = f2bf(tile[tc][oc]);     o.y = f2bf(tile[tc + 1][oc]);
    o.z = f2bf(tile[tc + 2][oc]); o.w = f2bf(tile[tc + 3][oc]);
    *(ushort4*)(out + (size_t)(c0 + oc) * M + (r0 + tc)) = o;
  }
}

// ---------------- grouped GEMM1: H = gelu(X@W1 + b1) ----------------
template <bool PRECONV>
__global__ __launch_bounds__(256) void gemm1_kernel(
    const u16* __restrict__ XB, const float* __restrict__ W1,
    const u16* __restrict__ W1T, const float* __restrict__ B1,
    const int* __restrict__ counts, const int* __restrict__ offsets,
    const int* __restrict__ slot_token, u16* __restrict__ H,
    int f_base, int F_sec)
{
  const int e    = blockIdx.y >> 6;
  const int rt   = blockIdx.y & 63;
  const int cnt  = counts[e];
  const int row0 = rt * 128;
  if (row0 >= cnt) return;
  const int off = offsets[e];
  const int n0  = blockIdx.x * 128;

  __shared__ __align__(16) u16 As[128 * 32];
  __shared__ __align__(16) u16 Bs[128 * 32]; // PRECONV: [n][k]; else [k][n]

  const int tid = threadIdx.x, wave = tid >> 6, lane = tid & 63;
  const int ca = wave * 64 + lane;
  const int rA0 = ca >> 2, sl0 = ca & 3;

  int t0 = slot_token[off + row0 + rA0];      if ((u32)t0 >= T_TOK) t0 = 0;
  int t1 = slot_token[off + row0 + rA0 + 64]; if ((u32)t1 >= T_TOK) t1 = 0;
  const char* gA0 = (const char*)XB + (((size_t)t0 * DDIM) + sl0 * 8) * 2;
  const char* gA1 = (const char*)XB + (((size_t)t1 * DDIM) + sl0 * 8) * 2;
  char* lA0 = (char*)As + wave * 1024;
  char* lA1 = (char*)As + 4096 + wave * 1024;

  const char* gB0 = nullptr; const char* gB1 = nullptr;
  char* lB0 = nullptr; char* lB1 = nullptr;
  if constexpr (PRECONV) {
    gB0 = (const char*)W1T + (((size_t)(e * FDIM + f_base + n0 + rA0)) * DDIM + sl0 * 8) * 2;
    gB1 = (const char*)W1T + (((size_t)(e * FDIM + f_base + n0 + rA0 + 64)) * DDIM + sl0 * 8) * 2;
    lB0 = (char*)Bs + wave * 1024;
    lB1 = (char*)Bs + 4096 + wave * 1024;
  }

  f32x4 acc[4][4] = {};
  const int wr = wave >> 1, wc = wave & 1;
  const int lr = lane & 15, lk = (lane >> 4) * 8;

  for (int k0 = 0; k0 < DDIM; k0 += 32) {
    __syncthreads();
    gload16(gA0 + k0 * 2, lA0);
    gload16(gA1 + k0 * 2, lA1);
    if constexpr (PRECONV) {
      gload16(gB0 + k0 * 2, lB0);
      gload16(gB1 + k0 * 2, lB1);
    } else {
      const int kk = wave * 8 + (lane >> 5);
      const int n4 = (lane & 31) * 4;
      #pragma unroll
      for (int p = 0; p < 4; p++) {
        int k = kk + p * 2;
        const float* src = W1 + (size_t)e * DDIM * FDIM + (size_t)(k0 + k) * FDIM + (f_base + n0 + n4);
        float4 v = *(const float4*)src;
        ushort4 o; o.x = f2bf(v.x); o.y = f2bf(v.y); o.z = f2bf(v.z); o.w = f2bf(v.w);
        *(ushort4*)&Bs[k * 128 + n4] = o;
      }
    }
    __syncthreads();

    short8 a[4], b[4];
    #pragma unroll
    for (int m = 0; m < 4; m++)
      a[m] = *(const short8*)&As[(wr * 64 + m * 16 + lr) * 32 + lk];
    #pragma unroll
    for (int n = 0; n < 4; n++) {
      if constexpr (PRECONV) {
        b[n] = *(const short8*)&Bs[(wc * 64 + n * 16 + lr) * 32 + lk];
      } else {
        int ncol = wc * 64 + n * 16 + lr;
        short8 tv;
        #pragma unroll
        for (int j = 0; j < 8; j++) tv[j] = (short)Bs[(lk + j) * 128 + ncol];
        b[n] = tv;
      }
    }
    #pragma unroll
    for (int m = 0; m < 4; m++)
      #pragma unroll
      for (int n = 0; n < 4; n++)
        acc[m][n] = __builtin_amdgcn_mfma_f32_16x16x32_bf16(a[m], b[n], acc[m][n], 0, 0, 0);
  }

  #pragma unroll
  for (int nn = 0; nn < 4; nn++) {
    int col = n0 + wc * 64 + nn * 16 + lr;
    float b1v = B1[e * FDIM + f_base + col];
    #pragma unroll
    for (int m = 0; m < 4; m++) {
      int rbase = wr * 64 + m * 16 + (lane >> 4) * 4;
      #pragma unroll
      for (int j = 0; j < 4; j++) {
        int r = rbase + j;
        if (row0 + r < cnt) {
          float v = acc[m][nn][j] + b1v;
          H[(size_t)(off + row0 + r) * F_sec + col] = f2bf(gelu_exact(v));
        }
      }
    }
  }
}

// ---------------- grouped GEMM2: Y = H@W2 (+b2) ----------------
// MODE 0: Y = v ; MODE 1: Y += v ; MODE 2: atomicAdd(out, w*v)
template <bool PRECONV, int MODE>
__global__ __launch_bounds__(256) void gemm2_kernel(
    const u16* __restrict__ H, const float* __restrict__ W2,
    const u16* __restrict__ W2T, const float* __restrict__ B2,
    const int* __restrict__ counts, const int* __restrict__ offsets,
    const int* __restrict__ slot_token, const float* __restrict__ slot_weight,
    float* __restrict__ Y, float* __restrict__ out,
    int f_base, int F_sec, int add_bias)
{
  const int e    = blockIdx.y >> 6;
  const int rt   = blockIdx.y & 63;
  const int cnt  = counts[e];
  const int row0 = rt * 128;
  if (row0 >= cnt) return;
  const int off = offsets[e];
  const int n0  = blockIdx.x * 128;

  __shared__ __align__(16) u16 As[128 * 32];
  __shared__ __align__(16) u16 Bs[128 * 32];

  const int tid = threadIdx.x, wave = tid >> 6, lane = tid & 63;
  const int ca = wave * 64 + lane;
  const int rA0 = ca >> 2, sl0 = ca & 3;

  const char* gA0 = (const char*)H + ((size_t)(off + row0 + rA0) * F_sec + sl0 * 8) * 2;
  const char* gA1 = (const char*)H + ((size_t)(off + row0 + rA0 + 64) * F_sec + sl0 * 8) * 2;
  char* lA0 = (char*)As + wave * 1024;
  char* lA1 = (char*)As + 4096 + wave * 1024;

  const char* gB0 = nullptr; const char* gB1 = nullptr;
  char* lB0 = nullptr; char* lB1 = nullptr;
  if constexpr (PRECONV) {
    gB0 = (const char*)W2T + ((size_t)(e * DDIM + n0 + rA0) * FDIM + f_base + sl0 * 8) * 2;
    gB1 = (const char*)W2T + ((size_t)(e * DDIM + n0 + rA0 + 64) * FDIM + f_base + sl0 * 8) * 2;
    lB0 = (char*)Bs + wave * 1024;
    lB1 = (char*)Bs + 4096 + wave * 1024;
  }

  f32x4 acc[4][4] = {};
  const int wr = wave >> 1, wc = wave & 1;
  const int lr = lane & 15, lk = (lane >> 4) * 8;

  for (int k0 = 0; k0 < F_sec; k0 += 32) {
    __syncthreads();
    gload16(gA0 + k0 * 2, lA0);
    gload16(gA1 + k0 * 2, lA1);
    if constexpr (PRECONV) {
      gload16(gB0 + k0 * 2, lB0);
      gload16(gB1 + k0 * 2, lB1);
    } else {
      const int kk = wave * 8 + (lane >> 5);
      const int n4 = (lane & 31) * 4;
      #pragma unroll
      for (int p = 0; p < 4; p++) {
        int k = kk + p * 2;
        const float* src = W2 + (size_t)e * FDIM * DDIM + (size_t)(f_base + k0 + k) * DDIM + (n0 + n4);
        float4 v = *(const float4*)src;
        ushort4 o; o.x = f2bf(v.x); o.y = f2bf(v.y); o.z = f2bf(v.z); o.w = f2bf(v.w);
        *(ushort4*)&Bs[k * 128 + n4] = o;
      }
    }
    __syncthreads();

    short8 a[4], b[4];
    #pragma unroll
    for (int m = 0; m < 4; m++)
      a[m] = *(const short8*)&As[(wr * 64 + m * 16 + lr) * 32 + lk];
    #pragma unroll
    for (int n = 0; n < 4; n++) {
      if constexpr (PRECONV) {
        b[n] = *(const short8*)&Bs[(wc * 64 + n * 16 + lr) * 32 + lk];
      } else {
        int ncol = wc * 64 + n * 16 + lr;
        short8 tv;
        #pragma unroll
        for (int j = 0; j < 8; j++) tv[j] = (short)Bs[(lk + j) * 128 + ncol];
        b[n] = tv;
      }
    }
    #pragma unroll
    for (int m = 0; m < 4; m++)
      #pragma unroll
      for (int n = 0; n < 4; n++)
        acc[m][n] = __builtin_amdgcn_mfma_f32_16x16x32_bf16(a[m], b[n], acc[m][n], 0, 0, 0);
  }

  #pragma unroll
  for (int m = 0; m < 4; m++) {
    int rbase = wr * 64 + m * 16 + (lane >> 4) * 4;
    #pragma unroll
    for (int j = 0; j < 4; j++) {
      int r = rbase + j;
      if (row0 + r >= cnt) continue;
      size_t s = (size_t)(off + row0 + r);
      int tok = 0; float wgt = 0.f;
      if constexpr (MODE == 2) { tok = slot_token[s]; wgt = slot_weight[s]; }
      #pragma unroll
      for (int nn = 0; nn < 4; nn++) {
        int col = n0 + wc * 64 + nn * 16 + lr;
        float v = acc[m][nn][j];
        if (add_bias) v += B2[e * DDIM + col];
        if constexpr (MODE == 0)      Y[s * DDIM + col] = v;
        else if constexpr (MODE == 1) Y[s * DDIM + col] += v;
        else atomicAdd(&out[(size_t)tok * DDIM + col], wgt * v);
      }
    }
  }
}

// ---------------- combine: out[t] = w0*Y[s0] + w1*Y[s1] ----------------
__global__ __launch_bounds__(256) void combine_kernel(
    const float* __restrict__ Y, const int* __restrict__ token_slot,
    const float* __restrict__ wts, float* __restrict__ out)
{
  size_t gid = (size_t)blockIdx.x * 256 + threadIdx.x;
  int t = (int)(gid >> 8);
  int c = (int)(gid & 255) * 4;
  int s0 = token_slot[t * 2], s1 = token_slot[t * 2 + 1];
  float w0 = wts[t * 2], w1 = wts[t * 2 + 1];
  float4 y0 = *(const float4*)&Y[(size_t)s0 * DDIM + c];
  float4 y1 = *(const float4*)&Y[(size_t)s1 * DDIM + c];
  float4 o;
  o.x = w0 * y0.x + w1 * y1.x; o.y = w0 * y0.y + w1 * y1.y;
  o.z = w0 * y0.z + w1 * y1.z; o.w = w0 * y0.w + w1 * y1.w;
  *(float4*)&out[(size_t)t * DDIM + c] = o;
}

extern "C" void kernel_launch(void* const* d_in, const int* in_sizes, int n_in,
                              void* d_out, int out_size, void* d_ws, size_t ws_size,
                              hipStream_t stream)
{
  (void)in_sizes; (void)n_in;
  const float* x  = (const float*)d_in[0];
  const float* gw = (const float*)d_in[1];
  const float* gb = (const float*)d_in[2];
  const float* w1 = (const float*)d_in[3];
  const float* b1 = (const float*)d_in[4];
  const float* w2 = (const float*)d_in[5];
  const float* b2 = (const float*)d_in[6];

  char* ws = (char*)d_ws;
  int*   counts  = (int*)(ws + 0);
  int*   posp    = (int*)(ws + 64);
  int*   offp    = (int*)(ws + 128);
  size_t off_sel   = 256;
  size_t off_wts   = off_sel + 65536;
  size_t off_stok  = off_wts + 65536;     // (16384+256) ints
  size_t off_swgt  = off_stok + 66560;
  size_t off_tslot = off_swgt + 66560;
  size_t off_end   = off_tslot + 65536;
  size_t off_xb    = (off_end + 1048575) & ~(size_t)1048575;

  int*   sel  = (int*)(ws + off_sel);
  float* wts  = (float*)(ws + off_wts);
  int*   stok = (int*)(ws + off_stok);
  float* swgt = (float*)(ws + off_swgt);
  int*   tslot= (int*)(ws + off_tslot);
  u16*   xb   = (u16*)(ws + off_xb);

  const size_t XB_SZ  = (size_t)T_TOK * DDIM * 2;
  const size_t WT_SZ  = (size_t)NEXP * DDIM * FDIM * 2; // one weight, bf16
  const size_t HROWS  = 2 * T_TOK + 128;
  const size_t Y_SZ   = (size_t)2 * T_TOK * DDIM * 4;
  size_t base = off_xb + XB_SZ;

  // tier selection
  struct Cfg { bool pre; int ns; bool useY; };
  const Cfg cands[] = { {true,1,true},{true,2,true},{true,4,true},{true,8,true},
                        {false,1,true},{false,2,true},{false,4,true},{false,8,true},
                        {false,8,false},{false,16,false} };
  Cfg cfg = cands[9];
  for (int i = 0; i < 10; i++) {
    size_t need = base;
    if (cands[i].pre) need += 2 * WT_SZ;
    need += HROWS * (size_t)(FDIM / cands[i].ns) * 2;
    if (cands[i].useY) need += Y_SZ;
    if (need <= ws_size) { cfg = cands[i]; break; }
  }

  size_t p = base;
  u16 *w1t = nullptr, *w2t = nullptr;
  if (cfg.pre) { w1t = (u16*)(ws + p); p += WT_SZ; w2t = (u16*)(ws + p); p += WT_SZ; }
  const int F_sec = FDIM / cfg.ns;
  u16* Hbuf = (u16*)(ws + p); p += HROWS * (size_t)F_sec * 2;
  float* Ybuf = cfg.useY ? (float*)(ws + p) : nullptr;

  hipMemsetAsync(ws, 0, 256, stream);
  router_kernel<<<T_TOK / 4, 256, 0, stream>>>(x, gw, gb, counts, sel, wts);
  scan_kernel<<<1, 64, 0, stream>>>(counts, offp, posp);
  slot_assign_kernel<<<T_TOK / 256, 256, 0, stream>>>(sel, wts, posp, stok, swgt, tslot);
  xconv_kernel<<<(T_TOK * DDIM / 8) / 256, 256, 0, stream>>>(x, xb);
  if (cfg.pre) {
    wtrans_kernel<<<dim3(FDIM / 64, DDIM / 64, NEXP), 256, 0, stream>>>(w1, w1t, DDIM, FDIM);
    wtrans_kernel<<<dim3(DDIM / 64, FDIM / 64, NEXP), 256, 0, stream>>>(w2, w2t, FDIM, DDIM);
  }
  if (!cfg.useY) hipMemsetAsync(d_out, 0, (size_t)out_size * sizeof(float), stream);

  for (int s = 0; s < cfg.ns; s++) {
    int fb = s * F_sec;
    dim3 g1(F_sec / 128, NEXP * 64);
    if (cfg.pre)
      gemm1_kernel<true><<<g1, 256, 0, stream>>>(xb, w1, w1t, b1, counts, offp, stok, Hbuf, fb, F_sec);
    else
      gemm1_kernel<false><<<g1, 256, 0, stream>>>(xb, w1, w1t, b1, counts, offp, stok, Hbuf, fb, F_sec);

    dim3 g2(DDIM / 128, NEXP * 64);
    int ab = (s == 0) ? 1 : 0;
    if (cfg.useY) {
      if (cfg.pre) {
        if (s == 0) gemm2_kernel<true, 0><<<g2, 256, 0, stream>>>(Hbuf, w2, w2t, b2, counts, offp, stok, swgt, Ybuf, (float*)d_out, fb, F_sec, ab);
        else        gemm2_kernel<true, 1><<<g2, 256, 0, stream>>>(Hbuf, w2, w2t, b2, counts, offp, stok, swgt, Ybuf, (float*)d_out, fb, F_sec, ab);
      } else {
        if (s == 0) gemm2_kernel<false, 0><<<g2, 256, 0, stream>>>(Hbuf, w2, w2t, b2, counts, offp, stok, swgt, Ybuf, (float*)d_out, fb, F_sec, ab);
        else        gemm2_kernel<false, 1><<<g2, 256, 0, stream>>>(Hbuf, w2, w2t, b2, counts, offp, stok, swgt, Ybuf, (float*)d_out, fb, F_sec, ab);
      }
    } else {
      gemm2_kernel<false, 2><<<g2, 256, 0, stream>>>(Hbuf, w2, w2t, b2, counts, offp, stok, swgt, Ybuf, (float*)d_out, fb, F_sec, ab);
    }
  }
  if (cfg.useY)
    combine_kernel<<<(T_TOK * DDIM / 4) / 256, 256, 0, stream>>>(Ybuf, tslot, wts, (float*)d_out);
}

// Round 2
// 922.958 us; speedup vs baseline: 1.0191x; 1.0191x over previous
//
#include <hip/hip_runtime.h>
#include <math.h>

#define T_TOK 8192
#define DDIM  1024
#define FDIM  4096
#define NEXP  8
#define MAXTILES 136

typedef __attribute__((ext_vector_type(8))) short short8;
typedef __attribute__((ext_vector_type(4))) float f32x4;
typedef unsigned short u16;
typedef unsigned int   u32;

typedef const __attribute__((address_space(1))) u32* gp_t;
typedef       __attribute__((address_space(3))) u32* lp_t;

__device__ __forceinline__ void gload16(const void* g, void* l) {
  __builtin_amdgcn_global_load_lds((gp_t)g, (lp_t)l, 16, 0, 0);
}

__device__ __forceinline__ u16 f2bf(float f) {
  u32 u = __float_as_uint(f);
  u = u + 0x7FFFu + ((u >> 16) & 1u);
  return (u16)(u >> 16);
}

__device__ __forceinline__ float gelu_exact(float v) {
  return 0.5f * v * (1.0f + erff(v * 0.70710678118654752440f));
}

// bijective XCD chunking (m204): consecutive logical ids land on one XCD
__device__ __forceinline__ int xcd_swz(int orig, int nwg) {
  int xcd = orig & 7;
  int q = nwg >> 3, r = nwg & 7;
  int base = (xcd < r) ? xcd * (q + 1) : r * (q + 1) + (xcd - r) * q;
  return base + (orig >> 3);
}

// ---------------- router (+ x->bf16 fused): one wave per token ----------------
__global__ __launch_bounds__(256) void router_kernel(
    const float* __restrict__ x, const float* __restrict__ gw,
    const float* __restrict__ gb, u16* __restrict__ xb,
    int* __restrict__ counts, int* __restrict__ sel, float* __restrict__ wts)
{
  const int t    = blockIdx.x * 4 + (threadIdx.x >> 6);
  const int lane = threadIdx.x & 63;
  const float* xr = x + (size_t)t * DDIM;
  u16* xbr = xb + (size_t)t * DDIM;
  float lg[NEXP];
  #pragma unroll
  for (int e = 0; e < NEXP; e++) lg[e] = 0.f;
  #pragma unroll
  for (int i = 0; i < 4; i++) {
    int d0 = i * 256 + lane * 4;
    float4 v = *(const float4*)(xr + d0);
    ushort4 o;
    o.x = f2bf(v.x); o.y = f2bf(v.y); o.z = f2bf(v.z); o.w = f2bf(v.w);
    *(ushort4*)(xbr + d0) = o;
    const float* g = gw + (size_t)d0 * NEXP;
    #pragma unroll
    for (int e = 0; e < NEXP; e++)
      lg[e] += v.x * g[e] + v.y * g[NEXP + e] + v.z * g[2 * NEXP + e] + v.w * g[3 * NEXP + e];
  }
  #pragma unroll
  for (int off = 32; off > 0; off >>= 1) {
    #pragma unroll
    for (int e = 0; e < NEXP; e++) lg[e] += __shfl_down(lg[e], off);
  }
  if (lane == 0) {
    float v0 = -1e30f, v1 = -1e30f; int s0 = 0, s1 = 0;
    #pragma unroll
    for (int e = 0; e < NEXP; e++) {
      float v = lg[e] + gb[e];
      if (v > v0) { v1 = v0; s1 = s0; v0 = v; s0 = e; }
      else if (v > v1) { v1 = v; s1 = e; }
    }
    float a  = expf(v1 - v0);
    float w0 = 1.f / (1.f + a);
    sel[t * 2] = s0; sel[t * 2 + 1] = s1;
    wts[t * 2] = w0; wts[t * 2 + 1] = 1.f - w0;
    atomicAdd(&counts[s0], 1); atomicAdd(&counts[s1], 1);
  }
}

// ---------------- scan + tile map ----------------
__global__ void scan_kernel(const int* __restrict__ counts,
                            int* __restrict__ offsets, int* __restrict__ pos,
                            int* __restrict__ map_e, int* __restrict__ map_r,
                            int* __restrict__ nT)
{
  if (threadIdx.x == 0) {
    int run = 0, nt = 0;
    for (int e = 0; e < NEXP; e++) {
      offsets[e] = run; pos[e] = run;
      int c = counts[e];
      int ntile = (c + 127) >> 7;
      for (int i = 0; i < ntile; i++) { map_e[nt] = e; map_r[nt] = i * 128; nt++; }
      run += c;
    }
    nT[0] = nt;
  }
}

__global__ __launch_bounds__(256) void slot_assign_kernel(
    const int* __restrict__ sel, const float* __restrict__ wts,
    int* __restrict__ pos, int* __restrict__ slot_token,
    float* __restrict__ slot_weight, int* __restrict__ token_slot)
{
  const int t = blockIdx.x * 256 + threadIdx.x;
  #pragma unroll
  for (int k = 0; k < 2; k++) {
    int e = sel[t * 2 + k];
    int p = atomicAdd(&pos[e], 1);
    slot_token[p] = t; slot_weight[p] = wts[t * 2 + k];
    token_slot[t * 2 + k] = p;
  }
}

// ---------------- weight transpose + bf16: in [M][N] f32 -> out [N][M] bf16 ----
__global__ __launch_bounds__(256) void wtrans_kernel(
    const float* __restrict__ in, u16* __restrict__ out, int M, int N)
{
  const int e = blockIdx.z;
  in  += (size_t)e * M * N;
  out += (size_t)e * M * N;
  const int c0 = blockIdx.x * 64;
  const int r0 = blockIdx.y * 64;
  __shared__ float tile[64][65];
  const int tid = threadIdx.x;
  const int tr = tid >> 4;
  const int tc = (tid & 15) * 4;
  #pragma unroll
  for (int p = 0; p < 4; p++) {
    int r = p * 16 + tr;
    float4 v = *(const float4*)(in + (size_t)(r0 + r) * N + (c0 + tc));
    tile[r][tc] = v.x; tile[r][tc + 1] = v.y; tile[r][tc + 2] = v.z; tile[r][tc + 3] = v.w;
  }
  __syncthreads();
  #pragma unroll
  for (int p = 0; p < 4; p++) {
    int oc = p * 16 + tr;
    ushort4 o;
    o.x = f2bf(tile[tc][oc]);     o.y = f2bf(tile[tc + 1][oc]);
    o.z = f2bf(tile[tc + 2][oc]); o.w = f2bf(tile[tc + 3][oc]);
    *(ushort4*)(out + (size_t)(c0 + oc) * M + (r0 + tc)) = o;
  }
}

// ---------------- grouped GEMM1: H = gelu(X@W1 + b1) ----------------
// 1D grid, n-major over [NTn][MAXTILES], XCD-chunked.
__global__ __launch_bounds__(256) void gemm1_kernel(
    const u16* __restrict__ XB, const u16* __restrict__ W1T,
    const float* __restrict__ B1,
    const int* __restrict__ counts, const int* __restrict__ offsets,
    const int* __restrict__ slot_token,
    const int* __restrict__ map_e, const int* __restrict__ map_r,
    const int* __restrict__ nT, u16* __restrict__ H)
{
  const int gid   = xcd_swz(blockIdx.x, gridDim.x);
  const int n_idx = gid / MAXTILES;
  const int t_idx = gid - n_idx * MAXTILES;
  if (t_idx >= nT[0]) return;
  const int e    = map_e[t_idx];
  const int row0 = map_r[t_idx];
  const int cnt  = counts[e];
  const int off  = offsets[e];
  const int n0   = n_idx * 128;

  __shared__ __align__(16) u16 As[128 * 32];
  __shared__ __align__(16) u16 Bs[128 * 32];

  const int tid = threadIdx.x, wave = tid >> 6, lane = tid & 63;
  const int ca = wave * 64 + lane;
  const int rA0 = ca >> 2, sl0 = ca & 3;

  int t0 = slot_token[off + row0 + rA0];      if ((u32)t0 >= T_TOK) t0 = 0;
  int t1 = slot_token[off + row0 + rA0 + 64]; if ((u32)t1 >= T_TOK) t1 = 0;
  const char* gA0 = (const char*)XB + (((size_t)t0 * DDIM) + sl0 * 8) * 2;
  const char* gA1 = (const char*)XB + (((size_t)t1 * DDIM) + sl0 * 8) * 2;
  char* lA0 = (char*)As + wave * 1024;
  char* lA1 = (char*)As + 4096 + wave * 1024;

  const char* gB0 = (const char*)W1T + (((size_t)(e * FDIM + n0 + rA0)) * DDIM + sl0 * 8) * 2;
  const char* gB1 = (const char*)W1T + (((size_t)(e * FDIM + n0 + rA0 + 64)) * DDIM + sl0 * 8) * 2;
  char* lB0 = (char*)Bs + wave * 1024;
  char* lB1 = (char*)Bs + 4096 + wave * 1024;

  f32x4 acc[4][4] = {};
  const int wr = wave >> 1, wc = wave & 1;
  const int lr = lane & 15, lk = (lane >> 4) * 8;

  for (int k0 = 0; k0 < DDIM; k0 += 32) {
    __syncthreads();
    gload16(gA0 + k0 * 2, lA0);
    gload16(gA1 + k0 * 2, lA1);
    gload16(gB0 + k0 * 2, lB0);
    gload16(gB1 + k0 * 2, lB1);
    __syncthreads();

    short8 a[4], b[4];
    #pragma unroll
    for (int m = 0; m < 4; m++)
      a[m] = *(const short8*)&As[(wr * 64 + m * 16 + lr) * 32 + lk];
    #pragma unroll
    for (int n = 0; n < 4; n++)
      b[n] = *(const short8*)&Bs[(wc * 64 + n * 16 + lr) * 32 + lk];
    #pragma unroll
    for (int m = 0; m < 4; m++)
      #pragma unroll
      for (int n = 0; n < 4; n++)
        acc[m][n] = __builtin_amdgcn_mfma_f32_16x16x32_bf16(a[m], b[n], acc[m][n], 0, 0, 0);
  }

  #pragma unroll
  for (int nn = 0; nn < 4; nn++) {
    int col = n0 + wc * 64 + nn * 16 + lr;
    float b1v = B1[e * FDIM + col];
    #pragma unroll
    for (int m = 0; m < 4; m++) {
      int rbase = wr * 64 + m * 16 + (lane >> 4) * 4;
      #pragma unroll
      for (int j = 0; j < 4; j++) {
        int r = rbase + j;
        if (row0 + r < cnt) {
          float v = acc[m][nn][j] + b1v;
          H[(size_t)(off + row0 + r) * FDIM + col] = f2bf(gelu_exact(v));
        }
      }
    }
  }
}

// ---------------- grouped GEMM2: Y = H@W2 + b2 ----------------
__global__ __launch_bounds__(256) void gemm2_kernel(
    const u16* __restrict__ H, const u16* __restrict__ W2T,
    const float* __restrict__ B2,
    const int* __restrict__ counts, const int* __restrict__ offsets,
    const int* __restrict__ map_e, const int* __restrict__ map_r,
    const int* __restrict__ nT, float* __restrict__ Y)
{
  const int gid   = xcd_swz(blockIdx.x, gridDim.x);
  const int n_idx = gid / MAXTILES;
  const int t_idx = gid - n_idx * MAXTILES;
  if (t_idx >= nT[0]) return;
  const int e    = map_e[t_idx];
  const int row0 = map_r[t_idx];
  const int cnt  = counts[e];
  const int off  = offsets[e];
  const int n0   = n_idx * 128;

  __shared__ __align__(16) u16 As[128 * 32];
  __shared__ __align__(16) u16 Bs[128 * 32];

  const int tid = threadIdx.x, wave = tid >> 6, lane = tid & 63;
  const int ca = wave * 64 + lane;
  const int rA0 = ca >> 2, sl0 = ca & 3;

  const char* gA0 = (const char*)H + ((size_t)(off + row0 + rA0) * FDIM + sl0 * 8) * 2;
  const char* gA1 = (const char*)H + ((size_t)(off + row0 + rA0 + 64) * FDIM + sl0 * 8) * 2;
  char* lA0 = (char*)As + wave * 1024;
  char* lA1 = (char*)As + 4096 + wave * 1024;

  const char* gB0 = (const char*)W2T + ((size_t)(e * DDIM + n0 + rA0) * FDIM + sl0 * 8) * 2;
  const char* gB1 = (const char*)W2T + ((size_t)(e * DDIM + n0 + rA0 + 64) * FDIM + sl0 * 8) * 2;
  char* lB0 = (char*)Bs + wave * 1024;
  char* lB1 = (char*)Bs + 4096 + wave * 1024;

  f32x4 acc[4][4] = {};
  const int wr = wave >> 1, wc = wave & 1;
  const int lr = lane & 15, lk = (lane >> 4) * 8;

  for (int k0 = 0; k0 < FDIM; k0 += 32) {
    __syncthreads();
    gload16(gA0 + k0 * 2, lA0);
    gload16(gA1 + k0 * 2, lA1);
    gload16(gB0 + k0 * 2, lB0);
    gload16(gB1 + k0 * 2, lB1);
    __syncthreads();

    short8 a[4], b[4];
    #pragma unroll
    for (int m = 0; m < 4; m++)
      a[m] = *(const short8*)&As[(wr * 64 + m * 16 + lr) * 32 + lk];
    #pragma unroll
    for (int n = 0; n < 4; n++)
      b[n] = *(const short8*)&Bs[(wc * 64 + n * 16 + lr) * 32 + lk];
    #pragma unroll
    for (int m = 0; m < 4; m++)
      #pragma unroll
      for (int n = 0; n < 4; n++)
        acc[m][n] = __builtin_amdgcn_mfma_f32_16x16x32_bf16(a[m], b[n], acc[m][n], 0, 0, 0);
  }

  #pragma unroll
  for (int m = 0; m < 4; m++) {
    int rbase = wr * 64 + m * 16 + (lane >> 4) * 4;
    #pragma unroll
    for (int j = 0; j < 4; j++) {
      int r = rbase + j;
      if (row0 + r >= cnt) continue;
      size_t s = (size_t)(off + row0 + r);
      #pragma unroll
      for (int nn = 0; nn < 4; nn++) {
        int col = n0 + wc * 64 + nn * 16 + lr;
        Y[s * DDIM + col] = acc[m][nn][j] + B2[e * DDIM + col];
      }
    }
  }
}

// ---------------- combine: out[t] = w0*Y[s0] + w1*Y[s1] ----------------
__global__ __launch_bounds__(256) void combine_kernel(
    const float* __restrict__ Y, const int* __restrict__ token_slot,
    const float* __restrict__ wts, float* __restrict__ out)
{
  size_t gid = (size_t)blockIdx.x * 256 + threadIdx.x;
  int t = (int)(gid >> 8);
  int c = (int)(gid & 255) * 4;
  int s0 = token_slot[t * 2], s1 = token_slot[t * 2 + 1];
  float w0 = wts[t * 2], w1 = wts[t * 2 + 1];
  float4 y0 = *(const float4*)&Y[(size_t)s0 * DDIM + c];
  float4 y1 = *(const float4*)&Y[(size_t)s1 * DDIM + c];
  float4 o;
  o.x = w0 * y0.x + w1 * y1.x; o.y = w0 * y0.y + w1 * y1.y;
  o.z = w0 * y0.z + w1 * y1.z; o.w = w0 * y0.w + w1 * y1.w;
  *(float4*)&out[(size_t)t * DDIM + c] = o;
}

extern "C" void kernel_launch(void* const* d_in, const int* in_sizes, int n_in,
                              void* d_out, int out_size, void* d_ws, size_t ws_size,
                              hipStream_t stream)
{
  (void)in_sizes; (void)n_in; (void)out_size; (void)ws_size;
  const float* x  = (const float*)d_in[0];
  const float* gw = (const float*)d_in[1];
  const float* gb = (const float*)d_in[2];
  const float* w1 = (const float*)d_in[3];
  const float* b1 = (const float*)d_in[4];
  const float* w2 = (const float*)d_in[5];
  const float* b2 = (const float*)d_in[6];

  char* ws = (char*)d_ws;
  int*   counts = (int*)(ws + 0);
  int*   posp   = (int*)(ws + 64);
  int*   offp   = (int*)(ws + 128);
  int*   nT     = (int*)(ws + 192);
  int*   map_e  = (int*)(ws + 256);
  int*   map_r  = (int*)(ws + 1024);

  size_t p = 2048;
  int*   sel   = (int*)(ws + p);   p += (size_t)T_TOK * 2 * 4;
  float* wts   = (float*)(ws + p); p += (size_t)T_TOK * 2 * 4;
  int*   stok  = (int*)(ws + p);  p += (size_t)(2 * T_TOK + 256) * 4;
  float* swgt  = (float*)(ws + p); p += (size_t)(2 * T_TOK + 256) * 4;
  int*   tslot = (int*)(ws + p);  p += (size_t)T_TOK * 2 * 4;
  p = (p + 1048575) & ~(size_t)1048575;
  u16*   xb    = (u16*)(ws + p);  p += (size_t)T_TOK * DDIM * 2;
  u16*   w1t   = (u16*)(ws + p);  p += (size_t)NEXP * DDIM * FDIM * 2;
  u16*   w2t   = (u16*)(ws + p);  p += (size_t)NEXP * DDIM * FDIM * 2;
  u16*   Hbuf  = (u16*)(ws + p);  p += (size_t)(2 * T_TOK + 128) * FDIM * 2;
  float* Ybuf  = (float*)(ws + p);

  hipMemsetAsync(ws, 0, 256, stream);
  router_kernel<<<T_TOK / 4, 256, 0, stream>>>(x, gw, gb, xb, counts, sel, wts);
  scan_kernel<<<1, 64, 0, stream>>>(counts, offp, posp, map_e, map_r, nT);
  slot_assign_kernel<<<T_TOK / 256, 256, 0, stream>>>(sel, wts, posp, stok, swgt, tslot);
  wtrans_kernel<<<dim3(FDIM / 64, DDIM / 64, NEXP), 256, 0, stream>>>(w1, w1t, DDIM, FDIM);
  wtrans_kernel<<<dim3(DDIM / 64, FDIM / 64, NEXP), 256, 0, stream>>>(w2, w2t, FDIM, DDIM);

  gemm1_kernel<<<(FDIM / 128) * MAXTILES, 256, 0, stream>>>(
      xb, w1t, b1, counts, offp, stok, map_e, map_r, nT, Hbuf);
  gemm2_kernel<<<(DDIM / 128) * MAXTILES, 256, 0, stream>>>(
      Hbuf, w2t, b2, counts, offp, map_e, map_r, nT, Ybuf);

  combine_kernel<<<(T_TOK * DDIM / 4) / 256, 256, 0, stream>>>(Ybuf, tslot, wts, (float*)d_out);
}